// Round 16
// baseline (70.745 us; speedup 1.0000x reference)
//
#include <hip/hip_runtime.h>
#include <math.h>

#define WIN 16   // +/- phoneme-index window (rounds 1..13 verified)
#define FPW 8    // frames per wave
#define NW  4    // waves per block
#define FPB (FPW * NW)   // 32 frames per block
#define CH  16   // staged rows per chunk (32 KB)
#define WP  40   // W row pitch (floats)

#define AS1 __attribute__((address_space(1)))
#define AS3 __attribute__((address_space(3)))

// Kernel 1: per-batch inclusive cumsum of durations (double precision scan),
// centers c[b,n] = cumsum(dur)[b,n] - 0.5*dur[b,n]   (verbatim)
__global__ void centers_kernel(const float* __restrict__ dur,
                               float* __restrict__ c, int N) {
    extern __shared__ double s[];
    int b = blockIdx.x;
    int n = threadIdx.x;
    float d = (n < N) ? dur[(size_t)b * N + n] : 0.0f;
    if (n < N) s[n] = (double)d;
    __syncthreads();
    for (int off = 1; off < N; off <<= 1) {
        double v = (n >= off && n < N) ? s[n - off] : 0.0;
        __syncthreads();
        if (n < N) s[n] += v;
        __syncthreads();
    }
    if (n < N) c[(size_t)b * N + n] = (float)(s[n] - 0.5 * (double)d);
}

// Kernel 1.5: per-frame window + FULL weight precompute. Search/adjust and
// m/sum expressions verbatim from the verified R13 bounds kernel; weights
// W[t][q] = exp(sc-m) * (1/sum) — same product/rounding the main kernel
// computed in R13. pack = a | (K<<16).
__global__ __launch_bounds__(256) void bounds_kernel(
    const float* __restrict__ c, const int* __restrict__ lens,
    int* __restrict__ pack, float* __restrict__ W, int N, int T) {
    int gt = blockIdx.x * 256 + threadIdx.x;   // over B*T
    int b = gt / T;
    int t = gt - b * T;
    const float* cb = c + (size_t)b * N;
    int L = lens[b];
    if (L < 1) L = 1;
    if (L > N) L = N;
    float tf = (float)t;
    int lo = 0, hi = L;
    while (lo < hi) {
        int mid = (lo + hi) >> 1;
        if (cb[mid] < tf) lo = mid + 1; else hi = mid;
    }
    int j = lo;
    if (j >= L) j = L - 1;
    float cj   = cb[j];
    float cjm1 = cb[(j > 0) ? (j - 1) : 0];
    if (j > 0 && (tf - cjm1) < (cj - tf)) j--;
    float dm = tf - cb[j];
    float m = -0.5f * dm * dm;                 // max of windowed scores
    int a = j - WIN; if (a < 0) a = 0;
    int e = j + WIN; if (e > L - 1) e = L - 1;
    int K = e - a + 1;
    pack[gt] = a | (K << 16);
    float* wr = W + (size_t)gt * WP;
    float sum = 0.0f;
    for (int k = a; k <= e; ++k) {
        float d  = tf - cb[k];
        float sc = -0.5f * d * d;
        float ev = __expf(sc - m);
        wr[k - a] = ev;
        sum += ev;
    }
    float inv = 1.0f / sum;
    for (int i = 0; i < K; ++i) wr[i] *= inv;
}

// Kernel 2: R13 structure (verified 56.2us) with two changes:
//  - weights are 8 predicated coalesced loads from precomputed W (no exp,
//    no c[] reads, no window math in the hot kernel)
//  - chunk loop starts at bid % nchunks (wrapped): desynchronizes the
//    per-chunk barrier/vmcnt drains across co-resident blocks (convoy
//    break). Reorders chunk summation: <=1e-5 f32 drift, threshold 0.1.
__global__ __launch_bounds__(256, 4) void upsample_w(
    const float* __restrict__ x,    // [B,N,H]
    const int* __restrict__ pack,   // [B,T] a | (K<<16)
    const float* __restrict__ W,    // [B,T,WP] weights
    float* __restrict__ out,        // [B,T,H]
    int B, int N, int H, int T) {
    __shared__ float rows[CH][512];        // 32 KB staged input rows (H=512)
    __shared__ int   bnd[2];               // block union window [n0, nEnd]

    int nwg = gridDim.x;
    int bid = blockIdx.x;
    if ((nwg & 7) == 0) {                  // XCD-bijective swizzle
        int cpx = nwg >> 3;
        bid = (bid & 7) * cpx + (bid >> 3);
    }
    int wave = threadIdx.x >> 6;
    int lane = threadIdx.x & 63;

    int tilesPerB = T / FPB;
    int b   = bid / tilesPerB;
    int t0  = (bid - b * tilesPerB) * FPB + wave * FPW;

    // ---- per-frame window params from precomputed pack ----
    const int* pb = pack + (size_t)b * T + t0;
    const float* wrow[FPW];
    int a[FPW], K[FPW];
    #pragma unroll
    for (int f = 0; f < FPW; ++f) {
        int pk = pb[f];
        a[f] = pk & 0xffff;
        K[f] = pk >> 16;
        wrow[f] = W + ((size_t)b * T + t0 + f) * WP;
    }

    // block union window: nearest index monotone in t
    if (wave == 0 && lane == 0) bnd[0] = a[0];
    if (wave == NW - 1 && lane == 0) bnd[1] = a[FPW - 1] + K[FPW - 1] - 1;
    __syncthreads();
    int n0   = bnd[0];
    int span = bnd[1] - n0 + 1;
    int nch  = (span + CH - 1) / CH;
    int rot  = bid % nch;                  // convoy-break phase offset

    const float* gbase = x + ((size_t)b * N + n0) * (size_t)H;

    float4 acc[FPW][2];
    #pragma unroll
    for (int f = 0; f < FPW; ++f) {
        acc[f][0] = make_float4(0.f, 0.f, 0.f, 0.f);
        acc[f][1] = make_float4(0.f, 0.f, 0.f, 0.f);
    }

    for (int ic = 0; ic < nch; ++ic) {
        int cidx = ic + rot; if (cidx >= nch) cidx -= nch;
        int kb = cidx * CH;
        int klen = span - kb; if (klen > CH) klen = CH;

        // ---- async stage (verbatim R8/R13): linear dest == linear read ----
        for (int r = wave; r < klen; r += NW) {
            const char* g = (const char*)(gbase + (size_t)(kb + r) * H);
            __builtin_amdgcn_global_load_lds(
                (const AS1 void*)(g + lane * 16),
                (AS3 void*)&rows[r][0], 16, 0, 0);
            __builtin_amdgcn_global_load_lds(
                (const AS1 void*)(g + 1024 + lane * 16),
                (AS3 void*)&rows[r][256], 16, 0, 0);
        }

        // ---- per-lane weights: 8 predicated coalesced W loads (overlaps
        //      the DMA; q wraps negative -> huge unsigned -> masked off) ----
        int nidx = n0 + kb + lane;
        float wv[FPW];
        #pragma unroll
        for (int f = 0; f < FPW; ++f) {
            unsigned q = (unsigned)(nidx - a[f]);
            wv[f] = (q < (unsigned)K[f]) ? wrow[f][q] : 0.0f;
        }
        __syncthreads();                   // DMA drained; rows resident

        // ---- fma from LDS, ascending k within chunk (verbatim R13) ----
        for (int k = 0; k < klen; ++k) {
            float wk[FPW];
            #pragma unroll
            for (int f = 0; f < FPW; ++f)
                wk[f] = __uint_as_float(
                    __builtin_amdgcn_readlane(__float_as_uint(wv[f]), k));
            const float4* row = (const float4*)rows[k];
            float4 va = row[lane];
            float4 vb = row[64 + lane];
            #pragma unroll
            for (int f = 0; f < FPW; ++f) {
                acc[f][0].x = fmaf(wk[f], va.x, acc[f][0].x);
                acc[f][0].y = fmaf(wk[f], va.y, acc[f][0].y);
                acc[f][0].z = fmaf(wk[f], va.z, acc[f][0].z);
                acc[f][0].w = fmaf(wk[f], va.w, acc[f][0].w);
                acc[f][1].x = fmaf(wk[f], vb.x, acc[f][1].x);
                acc[f][1].y = fmaf(wk[f], vb.y, acc[f][1].y);
                acc[f][1].z = fmaf(wk[f], vb.z, acc[f][1].z);
                acc[f][1].w = fmaf(wk[f], vb.w, acc[f][1].w);
            }
        }
        __syncthreads();                   // rows safe to overwrite
    }

    // ---- store the wave's 8 frames ----
    float* obase = out + ((size_t)b * T + t0) * (size_t)H;
    #pragma unroll
    for (int f = 0; f < FPW; ++f) {
        float4* o = (float4*)(obase + (size_t)f * H);
        o[lane]      = acc[f][0];
        o[64 + lane] = acc[f][1];
    }
}

extern "C" void kernel_launch(void* const* d_in, const int* in_sizes, int n_in,
                              void* d_out, int out_size, void* d_ws, size_t ws_size,
                              hipStream_t stream) {
    const float* x    = (const float*)d_in[0];  // [B,N,H] f32
    const int*   lens = (const int*)d_in[1];    // [B] int
    const float* dur  = (const float*)d_in[2];  // [B,N] f32

    int B  = in_sizes[1];
    int BN = in_sizes[2];
    int N  = BN / B;
    int H  = in_sizes[0] / BN;
    int T  = out_size / (B * H);

    size_t cB  = (size_t)B * N * sizeof(float);
    size_t pkB = (size_t)B * T * sizeof(int);

    float* c    = (float*)d_ws;
    int*   pk   = (int*)((char*)d_ws + cB);
    float* Wbuf = (float*)((char*)pk + pkB);    // B*T*WP floats (~10.5 MB)

    centers_kernel<<<B, N, N * sizeof(double), stream>>>(dur, c, N);
    bounds_kernel<<<(B * T) / 256, 256, 0, stream>>>(c, lens, pk, Wbuf, N, T);

    int blocks = (B * T) / FPB;             // 32 frames per block
    upsample_w<<<blocks, 256, 0, stream>>>(x, pk, Wbuf, (float*)d_out,
                                           B, N, H, T);
}

// Round 17
// 39.861 us; speedup vs baseline: 1.7748x; 1.7748x over previous
//
#include <hip/hip_runtime.h>
#include <math.h>

#define WIN 16       // hard cap: adaptive window always within +/-16 (R13-verified)
#define THRESH 20.0f // keep indices with score >= m - THRESH (e^-20 truncation)
#define FPW 8        // frames per wave
#define NW  4        // waves per block
#define FPB (FPW * NW)   // 32 frames per block
#define CH  16       // staged rows per chunk (32 KB)

#define AS1 __attribute__((address_space(1)))
#define AS3 __attribute__((address_space(3)))

// Kernel 1: per-batch inclusive cumsum of durations (double precision scan),
// centers c[b,n] = cumsum(dur)[b,n] - 0.5*dur[b,n]   (verbatim)
__global__ void centers_kernel(const float* __restrict__ dur,
                               float* __restrict__ c, int N) {
    extern __shared__ double s[];
    int b = blockIdx.x;
    int n = threadIdx.x;
    float d = (n < N) ? dur[(size_t)b * N + n] : 0.0f;
    if (n < N) s[n] = (double)d;
    __syncthreads();
    for (int off = 1; off < N; off <<= 1) {
        double v = (n >= off && n < N) ? s[n - off] : 0.0;
        __syncthreads();
        if (n < N) s[n] += v;
        __syncthreads();
    }
    if (n < N) c[(size_t)b * N + n] = (float)(s[n] - 0.5 * (double)d);
}

// Kernel 1.5: nearest index (verbatim R13 search) + ADAPTIVE window:
// scan outward from j while score >= m - THRESH (monotone |t-c| going out,
// so the kept set is contiguous), capped at j±WIN => always a subset of the
// R13-verified window. sum over [a,e] verbatim. pack = a | (K<<16).
__global__ __launch_bounds__(256) void bounds_kernel(
    const float* __restrict__ c, const int* __restrict__ lens,
    int* __restrict__ pack, float* __restrict__ marr,
    float* __restrict__ inv, int N, int T) {
    int gt = blockIdx.x * 256 + threadIdx.x;   // over B*T
    int b = gt / T;
    int t = gt - b * T;
    const float* cb = c + (size_t)b * N;
    int L = lens[b];
    if (L < 1) L = 1;
    if (L > N) L = N;
    float tf = (float)t;
    int lo = 0, hi = L;
    while (lo < hi) {
        int mid = (lo + hi) >> 1;
        if (cb[mid] < tf) lo = mid + 1; else hi = mid;
    }
    int j = lo;
    if (j >= L) j = L - 1;
    float cj   = cb[j];
    float cjm1 = cb[(j > 0) ? (j - 1) : 0];
    if (j > 0 && (tf - cjm1) < (cj - tf)) j--;
    float dm = tf - cb[j];
    float m = -0.5f * dm * dm;                 // max of windowed scores
    float lim = m - THRESH;
    int aCap = j - WIN; if (aCap < 0) aCap = 0;
    int eCap = j + WIN; if (eCap > L - 1) eCap = L - 1;
    int a = j, e = j;
    while (a > aCap) {
        float d = tf - cb[a - 1];
        if (-0.5f * d * d >= lim) --a; else break;
    }
    while (e < eCap) {
        float d = tf - cb[e + 1];
        if (-0.5f * d * d >= lim) ++e; else break;
    }
    float sum = 0.0f;
    for (int k = a; k <= e; ++k) {
        float d  = tf - cb[k];
        float sc = -0.5f * d * d;
        sum += __expf(sc - m);
    }
    pack[gt] = a | ((e - a + 1) << 16);
    marr[gt] = m;
    inv[gt]  = 1.0f / sum;
}

// Kernel 2: verbatim R13 structure (verified 56.2us) — stage CH rows via
// global_load_lds, per-lane weight from c + m + inv (identical expression),
// readlane broadcast, ascending-k fma. Only deltas: windows come from the
// adaptive pack (subset of R13's), and the block union is an explicit
// min/max reduce across waves (adaptive a/e not provably monotone).
__global__ __launch_bounds__(256, 4) void upsample_rl(
    const float* __restrict__ x,    // [B,N,H]
    const float* __restrict__ c,    // [B,N]
    const int* __restrict__ pack,   // [B,T] a | (K<<16)
    const float* __restrict__ marr, // [B,T] max score
    const float* __restrict__ inv,  // [B,T] softmax 1/sum
    float* __restrict__ out,        // [B,T,H]
    int B, int N, int H, int T) {
    __shared__ float rows[CH][512];        // 32 KB staged input rows (H=512)
    __shared__ int   bmin[NW], bmax[NW];   // per-wave window extremes

    int nwg = gridDim.x;
    int bid = blockIdx.x;
    if ((nwg & 7) == 0) {                  // XCD-bijective swizzle
        int cpx = nwg >> 3;
        bid = (bid & 7) * cpx + (bid >> 3);
    }
    int wave = threadIdx.x >> 6;
    int lane = threadIdx.x & 63;

    int tilesPerB = T / FPB;
    int b   = bid / tilesPerB;
    int t0  = (bid - b * tilesPerB) * FPB + wave * FPW;

    const float* cb = c + (size_t)b * N;

    // ---- per-frame window params (precomputed; wave-uniform loads) ----
    const int*   pb  = pack + (size_t)b * T + t0;
    const float* mb  = marr + (size_t)b * T + t0;
    const float* ivb = inv  + (size_t)b * T + t0;
    float tf[FPW], m_[FPW], iv[FPW];
    int a[FPW], K[FPW];
    int amin = 0x7fffffff, emax = 0;
    #pragma unroll
    for (int f = 0; f < FPW; ++f) {
        tf[f] = (float)(t0 + f);
        int pk = pb[f];
        a[f] = pk & 0xffff;
        K[f] = pk >> 16;
        m_[f] = mb[f];
        iv[f] = ivb[f];
        int ef = a[f] + K[f] - 1;
        if (a[f] < amin) amin = a[f];
        if (ef > emax)   emax = ef;
    }

    // ---- block union window: explicit min/max across the 4 waves ----
    if (lane == 0) { bmin[wave] = amin; bmax[wave] = emax; }
    __syncthreads();
    int n0 = min(min(bmin[0], bmin[1]), min(bmin[2], bmin[3]));
    int ne = max(max(bmax[0], bmax[1]), max(bmax[2], bmax[3]));
    int span = ne - n0 + 1;

    const float* gbase = x + ((size_t)b * N + n0) * (size_t)H;

    float4 acc[FPW][2];
    #pragma unroll
    for (int f = 0; f < FPW; ++f) {
        acc[f][0] = make_float4(0.f, 0.f, 0.f, 0.f);
        acc[f][1] = make_float4(0.f, 0.f, 0.f, 0.f);
    }

    for (int kb = 0; kb < span; kb += CH) {
        int klen = span - kb; if (klen > CH) klen = CH;

        // ---- async stage (verbatim R8/R13): linear dest == linear read ----
        for (int r = wave; r < klen; r += NW) {
            const char* g = (const char*)(gbase + (size_t)(kb + r) * H);
            __builtin_amdgcn_global_load_lds(
                (const AS1 void*)(g + lane * 16),
                (AS3 void*)&rows[r][0], 16, 0, 0);
            __builtin_amdgcn_global_load_lds(
                (const AS1 void*)(g + 1024 + lane * 16),
                (AS3 void*)&rows[r][256], 16, 0, 0);
        }

        // ---- per-lane weights (verbatim R13 expression; overlaps DMA) ----
        int nidx = n0 + kb + lane;
        int ci = nidx; if (ci > N - 1) ci = N - 1;
        float cv = cb[ci];
        float wv[FPW];
        #pragma unroll
        for (int f = 0; f < FPW; ++f) {
            float d  = tf[f] - cv;
            float wval = __expf(-0.5f * d * d - m_[f]) * iv[f];
            unsigned q = (unsigned)(nidx - a[f]);
            wv[f] = (q < (unsigned)K[f]) ? wval : 0.0f;
        }
        __syncthreads();                   // DMA drained; rows resident

        // ---- fma from LDS, ascending k; readlane broadcast (verbatim) ----
        for (int k = 0; k < klen; ++k) {
            float wk[FPW];
            #pragma unroll
            for (int f = 0; f < FPW; ++f)
                wk[f] = __uint_as_float(
                    __builtin_amdgcn_readlane(__float_as_uint(wv[f]), k));
            const float4* row = (const float4*)rows[k];
            float4 va = row[lane];
            float4 vb = row[64 + lane];
            #pragma unroll
            for (int f = 0; f < FPW; ++f) {
                acc[f][0].x = fmaf(wk[f], va.x, acc[f][0].x);
                acc[f][0].y = fmaf(wk[f], va.y, acc[f][0].y);
                acc[f][0].z = fmaf(wk[f], va.z, acc[f][0].z);
                acc[f][0].w = fmaf(wk[f], va.w, acc[f][0].w);
                acc[f][1].x = fmaf(wk[f], vb.x, acc[f][1].x);
                acc[f][1].y = fmaf(wk[f], vb.y, acc[f][1].y);
                acc[f][1].z = fmaf(wk[f], vb.z, acc[f][1].z);
                acc[f][1].w = fmaf(wk[f], vb.w, acc[f][1].w);
            }
        }
        __syncthreads();                   // rows safe to overwrite
    }

    // ---- store the wave's 8 frames ----
    float* obase = out + ((size_t)b * T + t0) * (size_t)H;
    #pragma unroll
    for (int f = 0; f < FPW; ++f) {
        float4* o = (float4*)(obase + (size_t)f * H);
        o[lane]      = acc[f][0];
        o[64 + lane] = acc[f][1];
    }
}

extern "C" void kernel_launch(void* const* d_in, const int* in_sizes, int n_in,
                              void* d_out, int out_size, void* d_ws, size_t ws_size,
                              hipStream_t stream) {
    const float* x    = (const float*)d_in[0];  // [B,N,H] f32
    const int*   lens = (const int*)d_in[1];    // [B] int
    const float* dur  = (const float*)d_in[2];  // [B,N] f32

    int B  = in_sizes[1];
    int BN = in_sizes[2];
    int N  = BN / B;
    int H  = in_sizes[0] / BN;
    int T  = out_size / (B * H);

    size_t cB  = (size_t)B * N * sizeof(float);
    size_t btB = (size_t)B * T * sizeof(int);

    float* c   = (float*)d_ws;
    int*   pk  = (int*)((char*)d_ws + cB);
    float* mar = (float*)((char*)pk + btB);
    float* ivr = (float*)((char*)mar + btB);

    centers_kernel<<<B, N, N * sizeof(double), stream>>>(dur, c, N);
    bounds_kernel<<<(B * T) / 256, 256, 0, stream>>>(c, lens, pk, mar, ivr, N, T);

    int blocks = (B * T) / FPB;             // 32 frames per block
    upsample_rl<<<blocks, 256, 0, stream>>>(x, c, pk, mar, ivr,
                                            (float*)d_out, B, N, H, T);
}